// Round 8
// baseline (547.440 us; speedup 1.0000x reference)
//
#include <hip/hip_runtime.h>

#define NN 50000
#define NE 600000
#define DD 128
#define XS 264   // padded LDS row stride in bf16 elems: 528 B = 33*16 (16B aligned), %32-dword offset 4 -> 2-way bank alias (free)
#define NB 49    // scan blocks: ceil(NN/1024)

typedef unsigned short u16;
typedef u16   u16x8  __attribute__((ext_vector_type(8)));
typedef u16   u16x4  __attribute__((ext_vector_type(4)));
typedef __bf16 bf16x8 __attribute__((ext_vector_type(8)));
typedef float f32x4  __attribute__((ext_vector_type(4)));

__device__ __forceinline__ u16 f2bf(float f) {  // RNE fp32->bf16
    unsigned u = __builtin_bit_cast(unsigned, f);
    u += 0x7FFFu + ((u >> 16) & 1u);
    return (u16)(u >> 16);
}

// node_features fp32 [NN,DD] -> bf16 table
__global__ void k_convert_nf(const float* __restrict__ nf, u16* __restrict__ out) {
    int id = blockIdx.x * 256 + threadIdx.x;            // NN*DD/4 threads exactly
    float4 v = ((const float4*)nf)[id];
    u16x4 o; o[0] = f2bf(v.x); o[1] = f2bf(v.y); o[2] = f2bf(v.z); o[3] = f2bf(v.w);
    ((u16x4*)out)[id] = o;
}

// Pack W[K,N] fp32 row-major into MFMA B-fragment order for 16x16x32
__global__ void k_pack(const float* __restrict__ W, u16* __restrict__ out, int K, int N) {
    int tid = blockIdx.x * 256 + threadIdx.x;
    if (tid >= K * N) return;
    int frag = tid >> 9, lane = (tid >> 3) & 63, j = tid & 7;
    int KT = K >> 5;
    int nt = frag / KT, kt = frag - nt * KT;
    int row = kt * 32 + ((lane >> 4) << 3) + j;
    int col = nt * 16 + (lane & 15);
    out[tid] = f2bf(W[row * N + col]);
}

// ---------------- counting sort of edges by destination (multi-block scan; validated r7) ----------------
__global__ void k_hist(const int* __restrict__ to_idx, int* __restrict__ cnt) {
    int e = blockIdx.x * 256 + threadIdx.x;
    if (e < NE) atomicAdd(&cnt[to_idx[e]], 1);
}

__global__ void k_scanA(const int* __restrict__ cnt, int* __restrict__ part, int* __restrict__ bsum) {
    __shared__ int s[1024];
    int tid = threadIdx.x;
    int g = blockIdx.x * 1024 + tid;
    int v = (g < NN) ? cnt[g] : 0;
    s[tid] = v;
    __syncthreads();
    for (int ofs = 1; ofs < 1024; ofs <<= 1) {
        int t = (tid >= ofs) ? s[tid - ofs] : 0;
        __syncthreads();
        s[tid] += t;
        __syncthreads();
    }
    if (g < NN) part[g] = s[tid] - v;           // exclusive within block
    if (tid == 1023) bsum[blockIdx.x] = s[1023];
}

__global__ void k_scanB(int* __restrict__ bsum) {
    __shared__ int s[64];
    int tid = threadIdx.x;
    int v = (tid < NB) ? bsum[tid] : 0;
    s[tid] = v;
    __syncthreads();
    for (int ofs = 1; ofs < 64; ofs <<= 1) {
        int t = (tid >= ofs) ? s[tid - ofs] : 0;
        __syncthreads();
        s[tid] += t;
        __syncthreads();
    }
    if (tid < NB) bsum[tid] = s[tid] - v;       // exclusive
}

__global__ void k_scanC(const int* __restrict__ part, const int* __restrict__ bsum, int* __restrict__ cursor) {
    int g = blockIdx.x * 256 + threadIdx.x;
    if (g < NN) cursor[g] = part[g] + bsum[g >> 10];
}

__global__ void k_reorder(const int* __restrict__ from_idx, const int* __restrict__ to_idx,
                          int* __restrict__ cursor, int* __restrict__ sf, int* __restrict__ st) {
    int e = blockIdx.x * 256 + threadIdx.x;
    if (e < NE) {
        int d = to_idx[e];
        int p = atomicAdd(&cursor[d], 1);
        sf[p] = from_idx[e];
        st[p] = d;
    }
}

// ---------------- edge kernel v6: same 64-edge block, 4 waves x 16 rows (2x TLP at same LDS) ----------------
// v5 math/memory byte-identical; only wave->row partition changes. LDS 33,792 B -> 4 blocks/CU,
// now 4 waves each -> 16 waves/CU (4/SIMD) vs v5's 8. Sorted edges + run-dedup (validated:
// WRITE 300->131 MB).
__global__ __launch_bounds__(256, 4) void k_edges(
    const u16* __restrict__ nf16, const int* __restrict__ sf,
    const int* __restrict__ st, const u16* __restrict__ pW0,
    const float* __restrict__ b0, const u16* __restrict__ pW1,
    const float* __restrict__ b1, float* __restrict__ agg)
{
    __shared__ u16 sX[64 * XS];
    const int tid = threadIdx.x;
    const int e0 = blockIdx.x * 64;

    // stage gather: 64 rows x 32 chunks of 8 bf16 (16 B); to-side rows repeat (sorted) -> cache-hot
    #pragma unroll
    for (int i = 0; i < 8; ++i) {
        int c = i * 256 + tid;
        int r = c >> 5, j = c & 31;
        int e = e0 + r;
        int node = (j < 16) ? sf[e] : st[e];
        *(u16x8*)(&sX[r * XS + j * 8]) = *(const u16x8*)(nf16 + node * DD + (j & 15) * 8);
    }
    __syncthreads();

    const int lane = tid & 63;
    const int wave = tid >> 6;      // 0..3
    const int base = wave * 16;     // each wave owns 16 rows (1 m-tile)
    const int l15  = lane & 15;
    const int quad = lane >> 4;
    const int arow0 = (base + l15) * XS + quad * 8;

    // consume X into registers (A-frags), freeing this wave's sX rows for H (wave-private)
    bf16x8 a[8];
    #pragma unroll
    for (int kt = 0; kt < 8; ++kt)
        a[kt] = __builtin_bit_cast(bf16x8, *(const u16x8*)(&sX[arow0 + kt * 32]));

    // layer 0: H[16,256] = relu(X @ W0 + b0)
    for (int nt = 0; nt < 16; ++nt) {
        f32x4 c0 = {0.f, 0.f, 0.f, 0.f};
        #pragma unroll
        for (int kt = 0; kt < 8; ++kt) {
            bf16x8 b = __builtin_bit_cast(bf16x8, *(const u16x8*)(pW0 + (nt * 8 + kt) * 512 + lane * 8));
            c0 = __builtin_amdgcn_mfma_f32_16x16x32_bf16(a[kt], b, c0, 0, 0, 0);
        }
        float bias = b0[nt * 16 + l15];
        #pragma unroll
        for (int i = 0; i < 4; ++i)
            sX[(base + quad * 4 + i) * XS + nt * 16 + l15] = f2bf(fmaxf(c0[i] + bias, 0.f));
    }

    // layer 1 A-frags from H (same rows, in-wave ordered: no barrier needed)
    #pragma unroll
    for (int kt = 0; kt < 8; ++kt)
        a[kt] = __builtin_bit_cast(bf16x8, *(const u16x8*)(&sX[arow0 + kt * 32]));

    // destinations for this lane's rows (sorted: non-decreasing)
    int tI[4];
    #pragma unroll
    for (int i = 0; i < 4; ++i)
        tI[i] = st[e0 + base + quad * 4 + i];

    // layer 1: m = relu(H @ W1 + b1); run-dedup scatter-add into agg
    for (int nt = 0; nt < 8; ++nt) {
        f32x4 c0 = {0.f, 0.f, 0.f, 0.f};
        #pragma unroll
        for (int kt = 0; kt < 8; ++kt) {
            bf16x8 b = __builtin_bit_cast(bf16x8, *(const u16x8*)(pW1 + (nt * 8 + kt) * 512 + lane * 8));
            c0 = __builtin_amdgcn_mfma_f32_16x16x32_bf16(a[kt], b, c0, 0, 0, 0);
        }
        float bias = b1[nt * 16 + l15];
        int col = nt * 16 + l15;
        float acc = fmaxf(c0[0] + bias, 0.f);
        #pragma unroll
        for (int i = 1; i < 4; ++i) {
            float v = fmaxf(c0[i] + bias, 0.f);
            if (tI[i] == tI[i - 1]) acc += v;
            else { unsafeAtomicAdd(&agg[(size_t)tI[i - 1] * DD + col], acc); acc = v; }
        }
        unsafeAtomicAdd(&agg[(size_t)tI[3] * DD + col], acc);
    }
}

// Node update v6: same re-partition — 64 nodes/block, 4 waves x 16 rows (16 waves/CU)
__global__ __launch_bounds__(256, 4) void k_update(
    const float* __restrict__ agg, const u16* __restrict__ nf16,
    const float* __restrict__ nf32, const u16* __restrict__ pW0,
    const float* __restrict__ b0, const u16* __restrict__ pW1,
    const float* __restrict__ b1, float* __restrict__ out)
{
    __shared__ u16 sX[64 * XS];
    const int tid = threadIdx.x;
    const int n0 = blockIdx.x * 64;

    // stage agg half (cols 0..127), fp32->bf16
    #pragma unroll
    for (int i = 0; i < 8; ++i) {
        int c = i * 256 + tid;
        int r = c >> 5, j = c & 31;
        int n = n0 + r;
        u16x4 o;
        if (n < NN) {
            float4 v = *(const float4*)(agg + (size_t)n * DD + j * 4);
            o[0] = f2bf(v.x); o[1] = f2bf(v.y); o[2] = f2bf(v.z); o[3] = f2bf(v.w);
        } else { o[0] = 0; o[1] = 0; o[2] = 0; o[3] = 0; }
        *(u16x4*)(&sX[r * XS + j * 4]) = o;
    }
    // stage nf half (cols 128..255), bf16 copy
    #pragma unroll
    for (int i = 0; i < 4; ++i) {
        int c = i * 256 + tid;
        int r = c >> 4, j = c & 15;
        int n = n0 + r;
        u16x8 v = {0, 0, 0, 0, 0, 0, 0, 0};
        if (n < NN) v = *(const u16x8*)(nf16 + (size_t)n * DD + j * 8);
        *(u16x8*)(&sX[r * XS + 128 + j * 8]) = v;
    }
    __syncthreads();

    const int lane = tid & 63;
    const int wave = tid >> 6;
    const int base = wave * 16;
    const int l15  = lane & 15;
    const int quad = lane >> 4;
    const int arow0 = (base + l15) * XS + quad * 8;

    bf16x8 a[8];
    #pragma unroll
    for (int kt = 0; kt < 8; ++kt)
        a[kt] = __builtin_bit_cast(bf16x8, *(const u16x8*)(&sX[arow0 + kt * 32]));

    for (int nt = 0; nt < 16; ++nt) {
        f32x4 c0 = {0.f, 0.f, 0.f, 0.f};
        #pragma unroll
        for (int kt = 0; kt < 8; ++kt) {
            bf16x8 b = __builtin_bit_cast(bf16x8, *(const u16x8*)(pW0 + (nt * 8 + kt) * 512 + lane * 8));
            c0 = __builtin_amdgcn_mfma_f32_16x16x32_bf16(a[kt], b, c0, 0, 0, 0);
        }
        float bias = b0[nt * 16 + l15];
        #pragma unroll
        for (int i = 0; i < 4; ++i)
            sX[(base + quad * 4 + i) * XS + nt * 16 + l15] = f2bf(fmaxf(c0[i] + bias, 0.f));
    }

    #pragma unroll
    for (int kt = 0; kt < 8; ++kt)
        a[kt] = __builtin_bit_cast(bf16x8, *(const u16x8*)(&sX[arow0 + kt * 32]));

    for (int nt = 0; nt < 8; ++nt) {
        f32x4 c0 = {0.f, 0.f, 0.f, 0.f};
        #pragma unroll
        for (int kt = 0; kt < 8; ++kt) {
            bf16x8 b = __builtin_bit_cast(bf16x8, *(const u16x8*)(pW1 + (nt * 8 + kt) * 512 + lane * 8));
            c0 = __builtin_amdgcn_mfma_f32_16x16x32_bf16(a[kt], b, c0, 0, 0, 0);
        }
        float bias = b1[nt * 16 + l15];
        int col = nt * 16 + l15;
        #pragma unroll
        for (int i = 0; i < 4; ++i) {
            int na = n0 + base + quad * 4 + i;
            if (na < NN) out[(size_t)na * DD + col] = nf32[(size_t)na * DD + col] + fmaxf(c0[i] + bias, 0.f);
        }
    }
}

extern "C" void kernel_launch(void* const* d_in, const int* in_sizes, int n_in,
                              void* d_out, int out_size, void* d_ws, size_t ws_size,
                              hipStream_t stream)
{
    const float* nf  = (const float*)d_in[0];
    const int* fidx  = (const int*)d_in[1];
    const int* tidx  = (const int*)d_in[2];
    const float* mW0 = (const float*)d_in[3];
    const float* mb0 = (const float*)d_in[4];
    const float* mW1 = (const float*)d_in[5];
    const float* mb1 = (const float*)d_in[6];
    const float* uW0 = (const float*)d_in[7];
    const float* ub0 = (const float*)d_in[8];
    const float* uW1 = (const float*)d_in[9];
    const float* ub1 = (const float*)d_in[10];
    float* out = (float*)d_out;

    char* ws = (char*)d_ws;
    u16*   nf16 = (u16*)ws;   ws += (size_t)NN * DD * 2;   // 12.8 MB
    float* agg  = (float*)ws; ws += (size_t)NN * DD * 4;   // 25.6 MB
    u16*   pmW0 = (u16*)ws;   ws += 256 * 256 * 2;
    u16*   pmW1 = (u16*)ws;   ws += 256 * 128 * 2;
    u16*   puW0 = (u16*)ws;   ws += 256 * 256 * 2;
    u16*   puW1 = (u16*)ws;   ws += 256 * 128 * 2;
    int*   cnt    = (int*)ws; ws += (size_t)NN * 4;        // 0.2 MB
    int*   cursor = (int*)ws; ws += (size_t)NN * 4;        // 0.2 MB
    int*   part   = (int*)ws; ws += (size_t)NN * 4;        // 0.2 MB
    int*   bsum   = (int*)ws; ws += 64 * 4;
    int*   sf     = (int*)ws; ws += (size_t)NE * 4;        // 2.4 MB
    int*   st     = (int*)ws; ws += (size_t)NE * 4;        // 2.4 MB

    hipMemsetAsync(agg, 0, (size_t)NN * DD * 4, stream);
    hipMemsetAsync(cnt, 0, (size_t)NN * 4, stream);
    k_convert_nf<<<(NN * DD / 4) / 256, 256, 0, stream>>>(nf, nf16);
    k_pack<<<256, 256, 0, stream>>>(mW0, pmW0, 256, 256);
    k_pack<<<128, 256, 0, stream>>>(mW1, pmW1, 256, 128);
    k_pack<<<256, 256, 0, stream>>>(uW0, puW0, 256, 256);
    k_pack<<<128, 256, 0, stream>>>(uW1, puW1, 256, 128);
    k_hist<<<(NE + 255) / 256, 256, 0, stream>>>(tidx, cnt);
    k_scanA<<<NB, 1024, 0, stream>>>(cnt, part, bsum);
    k_scanB<<<1, 64, 0, stream>>>(bsum);
    k_scanC<<<(NN + 255) / 256, 256, 0, stream>>>(part, bsum, cursor);
    k_reorder<<<(NE + 255) / 256, 256, 0, stream>>>(fidx, tidx, cursor, sf, st);
    k_edges<<<NE / 64, 256, 0, stream>>>(nf16, sf, st, pmW0, mb0, pmW1, mb1, agg);
    k_update<<<(NN + 63) / 64, 256, 0, stream>>>(agg, nf16, nf, puW0, ub0, puW1, ub1, out);
}

// Round 9
// 546.688 us; speedup vs baseline: 1.0014x; 1.0014x over previous
//
#include <hip/hip_runtime.h>

#define NN 50000
#define NE 600000
#define DD 128
#define XS 264   // padded LDS row stride in bf16 elems: 528 B = 33*16 (16B aligned), %32-dword offset 4 -> 2-way bank alias (free)
#define NB 49    // scan blocks: ceil(NN/1024)

typedef unsigned short u16;
typedef u16   u16x8  __attribute__((ext_vector_type(8)));
typedef u16   u16x4  __attribute__((ext_vector_type(4)));
typedef __bf16 bf16x8 __attribute__((ext_vector_type(8)));
typedef float f32x4  __attribute__((ext_vector_type(4)));

__device__ __forceinline__ u16 f2bf(float f) {  // RNE fp32->bf16
    unsigned u = __builtin_bit_cast(unsigned, f);
    u += 0x7FFFu + ((u >> 16) & 1u);
    return (u16)(u >> 16);
}

// node_features fp32 [NN,DD] -> bf16 table
__global__ void k_convert_nf(const float* __restrict__ nf, u16* __restrict__ out) {
    int id = blockIdx.x * 256 + threadIdx.x;            // NN*DD/4 threads exactly
    float4 v = ((const float4*)nf)[id];
    u16x4 o; o[0] = f2bf(v.x); o[1] = f2bf(v.y); o[2] = f2bf(v.z); o[3] = f2bf(v.w);
    ((u16x4*)out)[id] = o;
}

// Pack W[K,N] fp32 row-major into MFMA B-fragment order for 16x16x32
__global__ void k_pack(const float* __restrict__ W, u16* __restrict__ out, int K, int N) {
    int tid = blockIdx.x * 256 + threadIdx.x;
    if (tid >= K * N) return;
    int frag = tid >> 9, lane = (tid >> 3) & 63, j = tid & 7;
    int KT = K >> 5;
    int nt = frag / KT, kt = frag - nt * KT;
    int row = kt * 32 + ((lane >> 4) << 3) + j;
    int col = nt * 16 + (lane & 15);
    out[tid] = f2bf(W[row * N + col]);
}

// ---------------- counting sort of edges by destination (multi-block scan; validated r7) ----------------
__global__ void k_hist(const int* __restrict__ to_idx, int* __restrict__ cnt) {
    int e = blockIdx.x * 256 + threadIdx.x;
    if (e < NE) atomicAdd(&cnt[to_idx[e]], 1);
}

__global__ void k_scanA(const int* __restrict__ cnt, int* __restrict__ part, int* __restrict__ bsum) {
    __shared__ int s[1024];
    int tid = threadIdx.x;
    int g = blockIdx.x * 1024 + tid;
    int v = (g < NN) ? cnt[g] : 0;
    s[tid] = v;
    __syncthreads();
    for (int ofs = 1; ofs < 1024; ofs <<= 1) {
        int t = (tid >= ofs) ? s[tid - ofs] : 0;
        __syncthreads();
        s[tid] += t;
        __syncthreads();
    }
    if (g < NN) part[g] = s[tid] - v;           // exclusive within block
    if (tid == 1023) bsum[blockIdx.x] = s[1023];
}

__global__ void k_scanB(int* __restrict__ bsum) {
    __shared__ int s[64];
    int tid = threadIdx.x;
    int v = (tid < NB) ? bsum[tid] : 0;
    s[tid] = v;
    __syncthreads();
    for (int ofs = 1; ofs < 64; ofs <<= 1) {
        int t = (tid >= ofs) ? s[tid - ofs] : 0;
        __syncthreads();
        s[tid] += t;
        __syncthreads();
    }
    if (tid < NB) bsum[tid] = s[tid] - v;       // exclusive
}

__global__ void k_scanC(const int* __restrict__ part, const int* __restrict__ bsum, int* __restrict__ cursor) {
    int g = blockIdx.x * 256 + threadIdx.x;
    if (g < NN) cursor[g] = part[g] + bsum[g >> 10];
}

__global__ void k_reorder(const int* __restrict__ from_idx, const int* __restrict__ to_idx,
                          int* __restrict__ cursor, int* __restrict__ sf, int* __restrict__ st) {
    int e = blockIdx.x * 256 + threadIdx.x;
    if (e < NE) {
        int d = to_idx[e];
        int p = atomicAdd(&cursor[d], 1);
        sf[p] = from_idx[e];
        st[p] = d;
    }
}

// ---------------- edge kernel v7: 1 wave x 4 m-tiles (64 rows) -- max B-frag reuse + 4-way MFMA ILP ----------------
// v6 falsified TLP; mechanism analysis: (a) 8-kt MFMA chain per accumulator is latency-bound
// without >=2 independent chains, (b) each wave re-streams 192KB of weight frags from L2 per
// tile (L1 too small). 4 m-tiles/wave: 4 independent chains per B-frag load, weight L2 traffic
// halved vs v5 (197KB/64 edges = 1.85GB total). Single wave: barrier-free (in-order DS pipe).
// Sorted edges + run-dedup (validated: WRITE 300->131 MB). LDS 33.8KB -> 4 blocks/CU.
__global__ __launch_bounds__(64) void k_edges(
    const u16* __restrict__ nf16, const int* __restrict__ sf,
    const int* __restrict__ st, const u16* __restrict__ pW0,
    const float* __restrict__ b0, const u16* __restrict__ pW1,
    const float* __restrict__ b1, float* __restrict__ agg)
{
    __shared__ u16 sX[64 * XS];
    const int lane = threadIdx.x;   // 64 threads = 1 wave
    const int e0 = blockIdx.x * 64;

    // stage gather: 64 rows x 32 chunks of 8 bf16 (16 B); 2048 chunks / 64 lanes = 32 iters
    #pragma unroll
    for (int i = 0; i < 32; ++i) {
        int c = i * 64 + lane;
        int r = c >> 5, j = c & 31;
        int e = e0 + r;
        int node = (j < 16) ? sf[e] : st[e];
        *(u16x8*)(&sX[r * XS + j * 8]) = *(const u16x8*)(nf16 + node * DD + (j & 15) * 8);
    }
    // no __syncthreads: single wave, LDS ops in-order w.r.t. hazards

    const int l15  = lane & 15;
    const int quad = lane >> 4;

    // consume X fully into registers: 4 m-tiles x 8 k-tiles of A-frags (128 VGPRs)
    bf16x8 a[4][8];
    #pragma unroll
    for (int mt = 0; mt < 4; ++mt)
        #pragma unroll
        for (int kt = 0; kt < 8; ++kt)
            a[mt][kt] = __builtin_bit_cast(bf16x8, *(const u16x8*)(&sX[(mt * 16 + l15) * XS + kt * 32 + quad * 8]));

    // layer 0: H[64,256] = relu(X @ W0 + b0); each B-frag feeds 4 independent MFMA chains
    for (int nt = 0; nt < 16; ++nt) {
        f32x4 c[4];
        #pragma unroll
        for (int mt = 0; mt < 4; ++mt) c[mt] = (f32x4){0.f, 0.f, 0.f, 0.f};
        #pragma unroll
        for (int kt = 0; kt < 8; ++kt) {
            bf16x8 b = __builtin_bit_cast(bf16x8, *(const u16x8*)(pW0 + (nt * 8 + kt) * 512 + lane * 8));
            #pragma unroll
            for (int mt = 0; mt < 4; ++mt)
                c[mt] = __builtin_amdgcn_mfma_f32_16x16x32_bf16(a[mt][kt], b, c[mt], 0, 0, 0);
        }
        float bias = b0[nt * 16 + l15];
        #pragma unroll
        for (int mt = 0; mt < 4; ++mt)
            #pragma unroll
            for (int i = 0; i < 4; ++i)
                sX[(mt * 16 + quad * 4 + i) * XS + nt * 16 + l15] = f2bf(fmaxf(c[mt][i] + bias, 0.f));
    }

    // layer 1 A-frags from H (same wave wrote them; in-order DS pipe)
    #pragma unroll
    for (int mt = 0; mt < 4; ++mt)
        #pragma unroll
        for (int kt = 0; kt < 8; ++kt)
            a[mt][kt] = __builtin_bit_cast(bf16x8, *(const u16x8*)(&sX[(mt * 16 + l15) * XS + kt * 32 + quad * 8]));

    // destinations for this lane's rows (sorted: non-decreasing)
    int tI[4][4];
    #pragma unroll
    for (int mt = 0; mt < 4; ++mt)
        #pragma unroll
        for (int i = 0; i < 4; ++i)
            tI[mt][i] = st[e0 + mt * 16 + quad * 4 + i];

    // layer 1: m = relu(H @ W1 + b1); run-dedup scatter-add into agg
    for (int nt = 0; nt < 8; ++nt) {
        f32x4 c[4];
        #pragma unroll
        for (int mt = 0; mt < 4; ++mt) c[mt] = (f32x4){0.f, 0.f, 0.f, 0.f};
        #pragma unroll
        for (int kt = 0; kt < 8; ++kt) {
            bf16x8 b = __builtin_bit_cast(bf16x8, *(const u16x8*)(pW1 + (nt * 8 + kt) * 512 + lane * 8));
            #pragma unroll
            for (int mt = 0; mt < 4; ++mt)
                c[mt] = __builtin_amdgcn_mfma_f32_16x16x32_bf16(a[mt][kt], b, c[mt], 0, 0, 0);
        }
        float bias = b1[nt * 16 + l15];
        int col = nt * 16 + l15;
        #pragma unroll
        for (int mt = 0; mt < 4; ++mt) {
            float acc = fmaxf(c[mt][0] + bias, 0.f);
            #pragma unroll
            for (int i = 1; i < 4; ++i) {
                float v = fmaxf(c[mt][i] + bias, 0.f);
                if (tI[mt][i] == tI[mt][i - 1]) acc += v;
                else { unsafeAtomicAdd(&agg[(size_t)tI[mt][i - 1] * DD + col], acc); acc = v; }
            }
            unsafeAtomicAdd(&agg[(size_t)tI[mt][3] * DD + col], acc);
        }
    }
}

// Node update: r7-validated version (128 threads, 2 waves x 32 rows)
__global__ __launch_bounds__(128) void k_update(
    const float* __restrict__ agg, const u16* __restrict__ nf16,
    const float* __restrict__ nf32, const u16* __restrict__ pW0,
    const float* __restrict__ b0, const u16* __restrict__ pW1,
    const float* __restrict__ b1, float* __restrict__ out)
{
    __shared__ u16 sX[64 * XS];
    const int tid = threadIdx.x;
    const int n0 = blockIdx.x * 64;

    // stage agg half (cols 0..127), fp32->bf16
    #pragma unroll
    for (int i = 0; i < 16; ++i) {
        int c = i * 128 + tid;
        int r = c >> 5, j = c & 31;
        int n = n0 + r;
        u16x4 o;
        if (n < NN) {
            float4 v = *(const float4*)(agg + (size_t)n * DD + j * 4);
            o[0] = f2bf(v.x); o[1] = f2bf(v.y); o[2] = f2bf(v.z); o[3] = f2bf(v.w);
        } else { o[0] = 0; o[1] = 0; o[2] = 0; o[3] = 0; }
        *(u16x4*)(&sX[r * XS + j * 4]) = o;
    }
    // stage nf half (cols 128..255), bf16 copy
    #pragma unroll
    for (int i = 0; i < 8; ++i) {
        int c = i * 128 + tid;
        int r = c >> 4, j = c & 15;
        int n = n0 + r;
        u16x8 v = {0, 0, 0, 0, 0, 0, 0, 0};
        if (n < NN) v = *(const u16x8*)(nf16 + (size_t)n * DD + j * 8);
        *(u16x8*)(&sX[r * XS + 128 + j * 8]) = v;
    }
    __syncthreads();

    const int lane = tid & 63;
    const int wave = tid >> 6;
    const int base = wave * 32;
    const int l15  = lane & 15;
    const int quad = lane >> 4;
    const int arow0 = (base + l15) * XS + quad * 8;

    bf16x8 a[2][8];
    #pragma unroll
    for (int mt = 0; mt < 2; ++mt)
        #pragma unroll
        for (int kt = 0; kt < 8; ++kt)
            a[mt][kt] = __builtin_bit_cast(bf16x8, *(const u16x8*)(&sX[arow0 + mt * 16 * XS + kt * 32]));

    for (int nt = 0; nt < 16; ++nt) {
        f32x4 c0 = {0.f, 0.f, 0.f, 0.f}, c1 = {0.f, 0.f, 0.f, 0.f};
        #pragma unroll
        for (int kt = 0; kt < 8; ++kt) {
            bf16x8 b = __builtin_bit_cast(bf16x8, *(const u16x8*)(pW0 + (nt * 8 + kt) * 512 + lane * 8));
            c0 = __builtin_amdgcn_mfma_f32_16x16x32_bf16(a[0][kt], b, c0, 0, 0, 0);
            c1 = __builtin_amdgcn_mfma_f32_16x16x32_bf16(a[1][kt], b, c1, 0, 0, 0);
        }
        float bias = b0[nt * 16 + l15];
        #pragma unroll
        for (int i = 0; i < 4; ++i) {
            sX[(base +      quad * 4 + i) * XS + nt * 16 + l15] = f2bf(fmaxf(c0[i] + bias, 0.f));
            sX[(base + 16 + quad * 4 + i) * XS + nt * 16 + l15] = f2bf(fmaxf(c1[i] + bias, 0.f));
        }
    }

    #pragma unroll
    for (int mt = 0; mt < 2; ++mt)
        #pragma unroll
        for (int kt = 0; kt < 8; ++kt)
            a[mt][kt] = __builtin_bit_cast(bf16x8, *(const u16x8*)(&sX[arow0 + mt * 16 * XS + kt * 32]));

    for (int nt = 0; nt < 8; ++nt) {
        f32x4 c0 = {0.f, 0.f, 0.f, 0.f}, c1 = {0.f, 0.f, 0.f, 0.f};
        #pragma unroll
        for (int kt = 0; kt < 8; ++kt) {
            bf16x8 b = __builtin_bit_cast(bf16x8, *(const u16x8*)(pW1 + (nt * 8 + kt) * 512 + lane * 8));
            c0 = __builtin_amdgcn_mfma_f32_16x16x32_bf16(a[0][kt], b, c0, 0, 0, 0);
            c1 = __builtin_amdgcn_mfma_f32_16x16x32_bf16(a[1][kt], b, c1, 0, 0, 0);
        }
        float bias = b1[nt * 16 + l15];
        int col = nt * 16 + l15;
        #pragma unroll
        for (int i = 0; i < 4; ++i) {
            int na = n0 + base +      quad * 4 + i;
            int nb = n0 + base + 16 + quad * 4 + i;
            if (na < NN) out[(size_t)na * DD + col] = nf32[(size_t)na * DD + col] + fmaxf(c0[i] + bias, 0.f);
            if (nb < NN) out[(size_t)nb * DD + col] = nf32[(size_t)nb * DD + col] + fmaxf(c1[i] + bias, 0.f);
        }
    }
}

extern "C" void kernel_launch(void* const* d_in, const int* in_sizes, int n_in,
                              void* d_out, int out_size, void* d_ws, size_t ws_size,
                              hipStream_t stream)
{
    const float* nf  = (const float*)d_in[0];
    const int* fidx  = (const int*)d_in[1];
    const int* tidx  = (const int*)d_in[2];
    const float* mW0 = (const float*)d_in[3];
    const float* mb0 = (const float*)d_in[4];
    const float* mW1 = (const float*)d_in[5];
    const float* mb1 = (const float*)d_in[6];
    const float* uW0 = (const float*)d_in[7];
    const float* ub0 = (const float*)d_in[8];
    const float* uW1 = (const float*)d_in[9];
    const float* ub1 = (const float*)d_in[10];
    float* out = (float*)d_out;

    char* ws = (char*)d_ws;
    u16*   nf16 = (u16*)ws;   ws += (size_t)NN * DD * 2;   // 12.8 MB
    float* agg  = (float*)ws; ws += (size_t)NN * DD * 4;   // 25.6 MB
    u16*   pmW0 = (u16*)ws;   ws += 256 * 256 * 2;
    u16*   pmW1 = (u16*)ws;   ws += 256 * 128 * 2;
    u16*   puW0 = (u16*)ws;   ws += 256 * 256 * 2;
    u16*   puW1 = (u16*)ws;   ws += 256 * 128 * 2;
    int*   cnt    = (int*)ws; ws += (size_t)NN * 4;        // 0.2 MB
    int*   cursor = (int*)ws; ws += (size_t)NN * 4;        // 0.2 MB
    int*   part   = (int*)ws; ws += (size_t)NN * 4;        // 0.2 MB
    int*   bsum   = (int*)ws; ws += 64 * 4;
    int*   sf     = (int*)ws; ws += (size_t)NE * 4;        // 2.4 MB
    int*   st     = (int*)ws; ws += (size_t)NE * 4;        // 2.4 MB

    hipMemsetAsync(agg, 0, (size_t)NN * DD * 4, stream);
    hipMemsetAsync(cnt, 0, (size_t)NN * 4, stream);
    k_convert_nf<<<(NN * DD / 4) / 256, 256, 0, stream>>>(nf, nf16);
    k_pack<<<256, 256, 0, stream>>>(mW0, pmW0, 256, 256);
    k_pack<<<128, 256, 0, stream>>>(mW1, pmW1, 256, 128);
    k_pack<<<256, 256, 0, stream>>>(uW0, puW0, 256, 256);
    k_pack<<<128, 256, 0, stream>>>(uW1, puW1, 256, 128);
    k_hist<<<(NE + 255) / 256, 256, 0, stream>>>(tidx, cnt);
    k_scanA<<<NB, 1024, 0, stream>>>(cnt, part, bsum);
    k_scanB<<<1, 64, 0, stream>>>(bsum);
    k_scanC<<<(NN + 255) / 256, 256, 0, stream>>>(part, bsum, cursor);
    k_reorder<<<(NE + 255) / 256, 256, 0, stream>>>(fidx, tidx, cursor, sf, st);
    k_edges<<<NE / 64, 64, 0, stream>>>(nf16, sf, st, pmW0, mb0, pmW1, mb1, agg);
    k_update<<<(NN + 63) / 64, 128, 0, stream>>>(agg, nf16, nf, puW0, ub0, puW1, ub1, out);
}

// Round 10
// 456.078 us; speedup vs baseline: 1.2003x; 1.1987x over previous
//
#include <hip/hip_runtime.h>

#define NN 50000
#define NE 600000
#define DD 128
#define XS 264   // padded LDS row stride in bf16 elems: 528 B = 132 fp32 (exact fp32 reuse for m-buffer)
#define NB 49    // scan blocks: ceil(NN/1024)

typedef unsigned short u16;
typedef u16   u16x8  __attribute__((ext_vector_type(8)));
typedef u16   u16x4  __attribute__((ext_vector_type(4)));
typedef __bf16 bf16x8 __attribute__((ext_vector_type(8)));
typedef float f32x4  __attribute__((ext_vector_type(4)));

__device__ __forceinline__ u16 f2bf(float f) {  // RNE fp32->bf16
    unsigned u = __builtin_bit_cast(unsigned, f);
    u += 0x7FFFu + ((u >> 16) & 1u);
    return (u16)(u >> 16);
}

// node_features fp32 [NN,DD] -> bf16 table
__global__ void k_convert_nf(const float* __restrict__ nf, u16* __restrict__ out) {
    int id = blockIdx.x * 256 + threadIdx.x;            // NN*DD/4 threads exactly
    float4 v = ((const float4*)nf)[id];
    u16x4 o; o[0] = f2bf(v.x); o[1] = f2bf(v.y); o[2] = f2bf(v.z); o[3] = f2bf(v.w);
    ((u16x4*)out)[id] = o;
}

// Pack W[K,N] fp32 row-major into MFMA B-fragment order for 16x16x32
__global__ void k_pack(const float* __restrict__ W, u16* __restrict__ out, int K, int N) {
    int tid = blockIdx.x * 256 + threadIdx.x;
    if (tid >= K * N) return;
    int frag = tid >> 9, lane = (tid >> 3) & 63, j = tid & 7;
    int KT = K >> 5;
    int nt = frag / KT, kt = frag - nt * KT;
    int row = kt * 32 + ((lane >> 4) << 3) + j;
    int col = nt * 16 + (lane & 15);
    out[tid] = f2bf(W[row * N + col]);
}

// ---------------- counting sort of edges by destination (multi-block scan; validated r7) ----------------
__global__ void k_hist(const int* __restrict__ to_idx, int* __restrict__ cnt) {
    int e = blockIdx.x * 256 + threadIdx.x;
    if (e < NE) atomicAdd(&cnt[to_idx[e]], 1);
}

__global__ void k_scanA(const int* __restrict__ cnt, int* __restrict__ part, int* __restrict__ bsum) {
    __shared__ int s[1024];
    int tid = threadIdx.x;
    int g = blockIdx.x * 1024 + tid;
    int v = (g < NN) ? cnt[g] : 0;
    s[tid] = v;
    __syncthreads();
    for (int ofs = 1; ofs < 1024; ofs <<= 1) {
        int t = (tid >= ofs) ? s[tid - ofs] : 0;
        __syncthreads();
        s[tid] += t;
        __syncthreads();
    }
    if (g < NN) part[g] = s[tid] - v;           // exclusive within block
    if (tid == 1023) bsum[blockIdx.x] = s[1023];
}

__global__ void k_scanB(int* __restrict__ bsum) {
    __shared__ int s[64];
    int tid = threadIdx.x;
    int v = (tid < NB) ? bsum[tid] : 0;
    s[tid] = v;
    __syncthreads();
    for (int ofs = 1; ofs < 64; ofs <<= 1) {
        int t = (tid >= ofs) ? s[tid - ofs] : 0;
        __syncthreads();
        s[tid] += t;
        __syncthreads();
    }
    if (tid < NB) bsum[tid] = s[tid] - v;       // exclusive
}

__global__ void k_scanC(const int* __restrict__ part, const int* __restrict__ bsum, int* __restrict__ cursor) {
    int g = blockIdx.x * 256 + threadIdx.x;
    if (g < NN) cursor[g] = part[g] + bsum[g >> 10];
}

__global__ void k_reorder(const int* __restrict__ from_idx, const int* __restrict__ to_idx,
                          int* __restrict__ cursor, int* __restrict__ sf, int* __restrict__ st) {
    int e = blockIdx.x * 256 + threadIdx.x;
    if (e < NE) {
        int d = to_idx[e];
        int p = atomicAdd(&cursor[d], 1);
        sf[p] = from_idx[e];
        st[p] = d;
    }
}

// ---------------- edge kernel v8: v5 compute + block-level segmented reduction (atomics -> stores) ----------------
// Sorted edges => a destination's edge range is globally contiguous: within a block it is either
// INTERIOR (this block is sole writer -> plain store over memset-zeroed agg) or BOUNDARY (first/
// last run only, <=2/block -> atomicAdd). Layer-1 m goes to LDS as fp32 (64x132 = exact sX reuse),
// then a block-wide segmented reduction (thread=col; dest sequence wave-uniform -> uniform branches,
// coalesced 512B flushes). Atomics: 33M -> ~2.4M.
__global__ __launch_bounds__(128) void k_edges(
    const u16* __restrict__ nf16, const int* __restrict__ sf,
    const int* __restrict__ st, const u16* __restrict__ pW0,
    const float* __restrict__ b0, const u16* __restrict__ pW1,
    const float* __restrict__ b1, float* __restrict__ agg)
{
    __shared__ u16 sX[64 * XS];
    __shared__ int sDest[64];
    const int tid = threadIdx.x;
    const int e0 = blockIdx.x * 64;

    if (tid < 64) sDest[tid] = st[e0 + tid];
    // stage gather: 64 rows x 32 chunks of 8 bf16 (16 B); to-side rows repeat (sorted) -> cache-hot
    #pragma unroll
    for (int i = 0; i < 16; ++i) {
        int c = i * 128 + tid;
        int r = c >> 5, j = c & 31;
        int e = e0 + r;
        int node = (j < 16) ? sf[e] : st[e];
        *(u16x8*)(&sX[r * XS + j * 8]) = *(const u16x8*)(nf16 + node * DD + (j & 15) * 8);
    }
    __syncthreads();

    const int lane = tid & 63;
    const int wave = tid >> 6;
    const int base = wave * 32;
    const int l15  = lane & 15;
    const int quad = lane >> 4;
    const int arow0 = (base + l15) * XS + quad * 8;

    // consume X fully into registers (A-frags), freeing sX rows for H (rows wave-private)
    bf16x8 a[2][8];
    #pragma unroll
    for (int mt = 0; mt < 2; ++mt)
        #pragma unroll
        for (int kt = 0; kt < 8; ++kt)
            a[mt][kt] = __builtin_bit_cast(bf16x8, *(const u16x8*)(&sX[arow0 + mt * 16 * XS + kt * 32]));

    // layer 0: H[64,256] = relu(X @ W0 + b0)
    for (int nt = 0; nt < 16; ++nt) {
        f32x4 c0 = {0.f, 0.f, 0.f, 0.f}, c1 = {0.f, 0.f, 0.f, 0.f};
        #pragma unroll
        for (int kt = 0; kt < 8; ++kt) {
            bf16x8 b = __builtin_bit_cast(bf16x8, *(const u16x8*)(pW0 + (nt * 8 + kt) * 512 + lane * 8));
            c0 = __builtin_amdgcn_mfma_f32_16x16x32_bf16(a[0][kt], b, c0, 0, 0, 0);
            c1 = __builtin_amdgcn_mfma_f32_16x16x32_bf16(a[1][kt], b, c1, 0, 0, 0);
        }
        float bias = b0[nt * 16 + l15];
        #pragma unroll
        for (int i = 0; i < 4; ++i) {
            sX[(base +      quad * 4 + i) * XS + nt * 16 + l15] = f2bf(fmaxf(c0[i] + bias, 0.f));
            sX[(base + 16 + quad * 4 + i) * XS + nt * 16 + l15] = f2bf(fmaxf(c1[i] + bias, 0.f));
        }
    }

    // layer 1 A-frags from H (same rows, in-wave ordered: no barrier needed)
    #pragma unroll
    for (int mt = 0; mt < 2; ++mt)
        #pragma unroll
        for (int kt = 0; kt < 8; ++kt)
            a[mt][kt] = __builtin_bit_cast(bf16x8, *(const u16x8*)(&sX[arow0 + mt * 16 * XS + kt * 32]));

    __syncthreads();   // fence: u16 H-reads above must complete before fp32 m-writes below (TBAA)

    // layer 1: m = relu(H @ W1 + b1) -> fp32 into sM (reuses sX bytes; rows wave-private)
    float* sM = (float*)sX;   // [64][132] fp32 view, 132*4 = 264*2 bytes ✓
    for (int nt = 0; nt < 8; ++nt) {
        f32x4 c0 = {0.f, 0.f, 0.f, 0.f}, c1 = {0.f, 0.f, 0.f, 0.f};
        #pragma unroll
        for (int kt = 0; kt < 8; ++kt) {
            bf16x8 b = __builtin_bit_cast(bf16x8, *(const u16x8*)(pW1 + (nt * 8 + kt) * 512 + lane * 8));
            c0 = __builtin_amdgcn_mfma_f32_16x16x32_bf16(a[0][kt], b, c0, 0, 0, 0);
            c1 = __builtin_amdgcn_mfma_f32_16x16x32_bf16(a[1][kt], b, c1, 0, 0, 0);
        }
        float bias = b1[nt * 16 + l15];
        int col = nt * 16 + l15;
        #pragma unroll
        for (int i = 0; i < 4; ++i) {
            sM[(base +      quad * 4 + i) * 132 + col] = fmaxf(c0[i] + bias, 0.f);
            sM[(base + 16 + quad * 4 + i) * 132 + col] = fmaxf(c1[i] + bias, 0.f);
        }
    }
    __syncthreads();

    // block-wide segmented reduction over 64 sorted rows; thread = column (128 cols)
    const int head_d = sDest[0];
    const int tail_d = sDest[63];
    const bool head_sh = (e0 > 0) && (st[e0 - 1] == head_d);
    const bool tail_sh = (e0 + 64 < NE) && (st[e0 + 64] == tail_d);

    int dprev = head_d;
    float acc = sM[tid];          // row 0
    for (int r = 1; r < 64; ++r) {
        int d = sDest[r];         // wave-uniform -> uniform branch
        float v = sM[r * 132 + tid];
        if (d == dprev) acc += v;
        else {
            if ((dprev == head_d && head_sh) || (dprev == tail_d && tail_sh))
                unsafeAtomicAdd(&agg[(size_t)dprev * DD + tid], acc);
            else
                agg[(size_t)dprev * DD + tid] = acc;   // sole writer (interior run)
            acc = v; dprev = d;
        }
    }
    if ((dprev == head_d && head_sh) || (dprev == tail_d && tail_sh))
        unsafeAtomicAdd(&agg[(size_t)dprev * DD + tid], acc);
    else
        agg[(size_t)dprev * DD + tid] = acc;
}

// Node update: r7-validated version (128 threads, 2 waves x 32 rows)
__global__ __launch_bounds__(128) void k_update(
    const float* __restrict__ agg, const u16* __restrict__ nf16,
    const float* __restrict__ nf32, const u16* __restrict__ pW0,
    const float* __restrict__ b0, const u16* __restrict__ pW1,
    const float* __restrict__ b1, float* __restrict__ out)
{
    __shared__ u16 sX[64 * XS];
    const int tid = threadIdx.x;
    const int n0 = blockIdx.x * 64;

    // stage agg half (cols 0..127), fp32->bf16
    #pragma unroll
    for (int i = 0; i < 16; ++i) {
        int c = i * 128 + tid;
        int r = c >> 5, j = c & 31;
        int n = n0 + r;
        u16x4 o;
        if (n < NN) {
            float4 v = *(const float4*)(agg + (size_t)n * DD + j * 4);
            o[0] = f2bf(v.x); o[1] = f2bf(v.y); o[2] = f2bf(v.z); o[3] = f2bf(v.w);
        } else { o[0] = 0; o[1] = 0; o[2] = 0; o[3] = 0; }
        *(u16x4*)(&sX[r * XS + j * 4]) = o;
    }
    // stage nf half (cols 128..255), bf16 copy
    #pragma unroll
    for (int i = 0; i < 8; ++i) {
        int c = i * 128 + tid;
        int r = c >> 4, j = c & 15;
        int n = n0 + r;
        u16x8 v = {0, 0, 0, 0, 0, 0, 0, 0};
        if (n < NN) v = *(const u16x8*)(nf16 + (size_t)n * DD + j * 8);
        *(u16x8*)(&sX[r * XS + 128 + j * 8]) = v;
    }
    __syncthreads();

    const int lane = tid & 63;
    const int wave = tid >> 6;
    const int base = wave * 32;
    const int l15  = lane & 15;
    const int quad = lane >> 4;
    const int arow0 = (base + l15) * XS + quad * 8;

    bf16x8 a[2][8];
    #pragma unroll
    for (int mt = 0; mt < 2; ++mt)
        #pragma unroll
        for (int kt = 0; kt < 8; ++kt)
            a[mt][kt] = __builtin_bit_cast(bf16x8, *(const u16x8*)(&sX[arow0 + mt * 16 * XS + kt * 32]));

    for (int nt = 0; nt < 16; ++nt) {
        f32x4 c0 = {0.f, 0.f, 0.f, 0.f}, c1 = {0.f, 0.f, 0.f, 0.f};
        #pragma unroll
        for (int kt = 0; kt < 8; ++kt) {
            bf16x8 b = __builtin_bit_cast(bf16x8, *(const u16x8*)(pW0 + (nt * 8 + kt) * 512 + lane * 8));
            c0 = __builtin_amdgcn_mfma_f32_16x16x32_bf16(a[0][kt], b, c0, 0, 0, 0);
            c1 = __builtin_amdgcn_mfma_f32_16x16x32_bf16(a[1][kt], b, c1, 0, 0, 0);
        }
        float bias = b0[nt * 16 + l15];
        #pragma unroll
        for (int i = 0; i < 4; ++i) {
            sX[(base +      quad * 4 + i) * XS + nt * 16 + l15] = f2bf(fmaxf(c0[i] + bias, 0.f));
            sX[(base + 16 + quad * 4 + i) * XS + nt * 16 + l15] = f2bf(fmaxf(c1[i] + bias, 0.f));
        }
    }

    #pragma unroll
    for (int mt = 0; mt < 2; ++mt)
        #pragma unroll
        for (int kt = 0; kt < 8; ++kt)
            a[mt][kt] = __builtin_bit_cast(bf16x8, *(const u16x8*)(&sX[arow0 + mt * 16 * XS + kt * 32]));

    for (int nt = 0; nt < 8; ++nt) {
        f32x4 c0 = {0.f, 0.f, 0.f, 0.f}, c1 = {0.f, 0.f, 0.f, 0.f};
        #pragma unroll
        for (int kt = 0; kt < 8; ++kt) {
            bf16x8 b = __builtin_bit_cast(bf16x8, *(const u16x8*)(pW1 + (nt * 8 + kt) * 512 + lane * 8));
            c0 = __builtin_amdgcn_mfma_f32_16x16x32_bf16(a[0][kt], b, c0, 0, 0, 0);
            c1 = __builtin_amdgcn_mfma_f32_16x16x32_bf16(a[1][kt], b, c1, 0, 0, 0);
        }
        float bias = b1[nt * 16 + l15];
        int col = nt * 16 + l15;
        #pragma unroll
        for (int i = 0; i < 4; ++i) {
            int na = n0 + base +      quad * 4 + i;
            int nb = n0 + base + 16 + quad * 4 + i;
            if (na < NN) out[(size_t)na * DD + col] = nf32[(size_t)na * DD + col] + fmaxf(c0[i] + bias, 0.f);
            if (nb < NN) out[(size_t)nb * DD + col] = nf32[(size_t)nb * DD + col] + fmaxf(c1[i] + bias, 0.f);
        }
    }
}

extern "C" void kernel_launch(void* const* d_in, const int* in_sizes, int n_in,
                              void* d_out, int out_size, void* d_ws, size_t ws_size,
                              hipStream_t stream)
{
    const float* nf  = (const float*)d_in[0];
    const int* fidx  = (const int*)d_in[1];
    const int* tidx  = (const int*)d_in[2];
    const float* mW0 = (const float*)d_in[3];
    const float* mb0 = (const float*)d_in[4];
    const float* mW1 = (const float*)d_in[5];
    const float* mb1 = (const float*)d_in[6];
    const float* uW0 = (const float*)d_in[7];
    const float* ub0 = (const float*)d_in[8];
    const float* uW1 = (const float*)d_in[9];
    const float* ub1 = (const float*)d_in[10];
    float* out = (float*)d_out;

    char* ws = (char*)d_ws;
    u16*   nf16 = (u16*)ws;   ws += (size_t)NN * DD * 2;   // 12.8 MB
    float* agg  = (float*)ws; ws += (size_t)NN * DD * 4;   // 25.6 MB
    u16*   pmW0 = (u16*)ws;   ws += 256 * 256 * 2;
    u16*   pmW1 = (u16*)ws;   ws += 256 * 128 * 2;
    u16*   puW0 = (u16*)ws;   ws += 256 * 256 * 2;
    u16*   puW1 = (u16*)ws;   ws += 256 * 128 * 2;
    int*   cnt    = (int*)ws; ws += (size_t)NN * 4;        // 0.2 MB
    int*   cursor = (int*)ws; ws += (size_t)NN * 4;        // 0.2 MB
    int*   part   = (int*)ws; ws += (size_t)NN * 4;        // 0.2 MB
    int*   bsum   = (int*)ws; ws += 64 * 4;
    int*   sf     = (int*)ws; ws += (size_t)NE * 4;        // 2.4 MB
    int*   st     = (int*)ws; ws += (size_t)NE * 4;        // 2.4 MB

    hipMemsetAsync(agg, 0, (size_t)NN * DD * 4, stream);
    hipMemsetAsync(cnt, 0, (size_t)NN * 4, stream);
    k_convert_nf<<<(NN * DD / 4) / 256, 256, 0, stream>>>(nf, nf16);
    k_pack<<<256, 256, 0, stream>>>(mW0, pmW0, 256, 256);
    k_pack<<<128, 256, 0, stream>>>(mW1, pmW1, 256, 128);
    k_pack<<<256, 256, 0, stream>>>(uW0, puW0, 256, 256);
    k_pack<<<128, 256, 0, stream>>>(uW1, puW1, 256, 128);
    k_hist<<<(NE + 255) / 256, 256, 0, stream>>>(tidx, cnt);
    k_scanA<<<NB, 1024, 0, stream>>>(cnt, part, bsum);
    k_scanB<<<1, 64, 0, stream>>>(bsum);
    k_scanC<<<(NN + 255) / 256, 256, 0, stream>>>(part, bsum, cursor);
    k_reorder<<<(NE + 255) / 256, 256, 0, stream>>>(fidx, tidx, cursor, sf, st);
    k_edges<<<NE / 64, 128, 0, stream>>>(nf16, sf, st, pmW0, mb0, pmW1, mb1, agg);
    k_update<<<(NN + 63) / 64, 128, 0, stream>>>(agg, nf16, nf, puW0, ub0, puW1, ub1, out);
}